// Round 7
// baseline (55.886 us; speedup 1.0000x reference)
//
#include <hip/hip_runtime.h>
#include <hip/hip_bf16.h>

// Locally-connected 2D: out[b,o,y,x] = sum_{c,kh,kw} x[b,c,y+kh,x+kw] * W[y,x,o,c*25+kh*5+kw] + b[y,x,o]
// x: [128,3,64,64] f32, W: [60,60,32,75] f32, bias: [60,60,32] f32, out: [128,32,60,60] f32.
//
// k1: one block = 4 consecutive x positions (900 blocks, bijective XCD swizzle).
// k-order k'=(c*5+kh)*8+w, w in [0,8) = x-window offset. Patches staged ONCE in LDS
// (ds_write_b128 rows), A-fragments hoisted to registers after the single barrier.
// W never touches LDS: each lane loads its own B-fragment source (5 floats per
// (o, c*5+kh) group) straight from global and shift-packs it in registers with
// compile-time xi shifts -> the position loop has NO barriers, NO LDS traffic for W,
// no store drains. Latency hidden by 4 blocks/CU x 4 waves free-running.
// Epilogue -> tmp[pos][b*32+o] (coalesced); k2 transposes tmp -> out.

#define RY 60
#define RX 60
#define OC 32
#define BATCH 128
#define CIN 3
#define HW 64
#define XT 4
#define KP 136   // pa row stride (u16): 272 B -> conflict-light; [120,136) zero pad

typedef __attribute__((ext_vector_type(8))) short short8;
typedef __attribute__((ext_vector_type(4))) float f32x4;

__device__ __forceinline__ ushort bf16u(float f) {
    __hip_bfloat16 h = __float2bfloat16(f);
    return *reinterpret_cast<ushort*>(&h);
}
__device__ __forceinline__ unsigned pk2(float a, float b) {
    return (unsigned)bf16u(a) | ((unsigned)bf16u(b) << 16);
}

template<bool COAL>
__global__ __launch_bounds__(256, 4) void lc2d_k1(
    const float* __restrict__ x, const float* __restrict__ w,
    const float* __restrict__ bias, float* __restrict__ outp,
    float* __restrict__ tmp)
{
    __shared__ ushort pa[BATCH][KP];   // 34816 B -> 4 blocks/CU

    const int tid = threadIdx.x;
    // bijective XCD swizzle for 900 blocks: q=112, r=4
    const int id  = blockIdx.x;
    const int xcd = id & 7, ii = id >> 3;
    const int lin = (xcd < 4 ? xcd * 113 : 452 + (xcd - 4) * 112) + ii;
    const int y   = lin / 15;
    const int xg  = lin - y * 15;
    const int x0  = xg * 4;
    const int pos0 = y * RX + x0;

    const int lane = tid & 63;
    const int lrow = lane & 15;
    const int lgrp = lane >> 4;
    const int wid  = tid >> 6;
    const int mbase = wid * 32;

    // ---- bias prefetch ----
    float bb[XT][2];
    #pragma unroll
    for (int xi = 0; xi < XT; ++xi) {
        bb[xi][0] = bias[(size_t)(pos0 + xi) * OC + lrow];
        bb[xi][1] = bias[(size_t)(pos0 + xi) * OC + 16 + lrow];
    }

    // ---- stage patches once: row = (b, cm=c*5+kh), 8 floats -> one b128 write ----
    #pragma unroll
    for (int i = 0; i < 8; ++i) {
        const int r = tid + i * 256;
        if (i < 7 || r < BATCH * 15) {
            const int b  = r / 15;
            const int cm = r - b * 15;
            const int c  = cm / 5;
            const int kh = cm - c * 5;
            const float* src = x + (size_t)((b * CIN + c) * HW + (y + kh)) * HW + x0;
            const float4 v0 = *(const float4*)(src);       // x0 % 4 == 0 -> aligned
            const float4 v1 = *(const float4*)(src + 4);
            *reinterpret_cast<uint4*>(&pa[b][cm * 8]) =
                make_uint4(pk2(v0.x, v0.y), pk2(v0.z, v0.w),
                           pk2(v1.x, v1.y), pk2(v1.z, v1.w));
        }
    }
    if (tid < 128) {   // zero pa[b][120..136)
        *reinterpret_cast<uint4*>(&pa[tid][120]) = make_uint4(0u, 0u, 0u, 0u);
        *reinterpret_cast<uint4*>(&pa[tid][128]) = make_uint4(0u, 0u, 0u, 0u);
    }
    __syncthreads();   // the ONLY barrier

    // ---- hoist A-fragments (reused by all 4 positions) ----
    short8 af[4][2];
    #pragma unroll
    for (int ks = 0; ks < 4; ++ks) {
        const int koff = ks * 32 + lgrp * 8;
        af[ks][0] = *(const short8*)&pa[mbase + lrow][koff];
        af[ks][1] = *(const short8*)&pa[mbase + 16 + lrow][koff];
    }

    // ---- per-lane W offsets (position-invariant): frag (nt,ks) -> 5 floats ----
    int woff[2][4];
    #pragma unroll
    for (int nt = 0; nt < 2; ++nt)
        #pragma unroll
        for (int ks = 0; ks < 4; ++ks)
            woff[nt][ks] = (nt * 16 + lrow) * 75 + (ks * 4 + lgrp) * 5;

    // ---- position loop: no sync, no LDS for W ----
    #pragma unroll
    for (int xi = 0; xi < XT; ++xi) {
        const float* wp = w + (size_t)(pos0 + xi) * (OC * 75);

        // issue all 40 W loads for this position
        float wr[2][4][5];
        #pragma unroll
        for (int nt = 0; nt < 2; ++nt)
            #pragma unroll
            for (int ks = 0; ks < 4; ++ks) {
                const float* s = wp + woff[nt][ks];
                #pragma unroll
                for (int j = 0; j < 5; ++j) wr[nt][ks][j] = s[j];
            }

        // shift-pack into B fragments (xi is compile-time in the unrolled loop)
        short8 bfr[2][4];
        #pragma unroll
        for (int nt = 0; nt < 2; ++nt)
            #pragma unroll
            for (int ks = 0; ks < 4; ++ks) {
                unsigned wd[4] = {0u, 0u, 0u, 0u};
                #pragma unroll
                for (int kw = 0; kw < 5; ++kw) {
                    const int ws = xi + kw;
                    wd[ws >> 1] |= (unsigned)bf16u(wr[nt][ks][kw]) << ((ws & 1) * 16);
                }
                union { unsigned u[4]; short8 s; } cv;
                cv.u[0] = wd[0]; cv.u[1] = wd[1]; cv.u[2] = wd[2]; cv.u[3] = wd[3];
                bfr[nt][ks] = cv.s;
            }

        f32x4 acc[2][2];
        #pragma unroll
        for (int mt = 0; mt < 2; ++mt)
            #pragma unroll
            for (int nt = 0; nt < 2; ++nt)
                acc[mt][nt] = (f32x4){0.f, 0.f, 0.f, 0.f};

        #pragma unroll
        for (int ks = 0; ks < 4; ++ks) {
            acc[0][0] = __builtin_amdgcn_mfma_f32_16x16x32_bf16(af[ks][0], bfr[0][ks], acc[0][0], 0, 0, 0);
            acc[0][1] = __builtin_amdgcn_mfma_f32_16x16x32_bf16(af[ks][0], bfr[1][ks], acc[0][1], 0, 0, 0);
            acc[1][0] = __builtin_amdgcn_mfma_f32_16x16x32_bf16(af[ks][1], bfr[0][ks], acc[1][0], 0, 0, 0);
            acc[1][1] = __builtin_amdgcn_mfma_f32_16x16x32_bf16(af[ks][1], bfr[1][ks], acc[1][1], 0, 0, 0);
        }

        const int pos = pos0 + xi;
        if (COAL) {
            float* tb = tmp + (size_t)pos * (BATCH * OC);
            #pragma unroll
            for (int mt = 0; mt < 2; ++mt)
                #pragma unroll
                for (int nt = 0; nt < 2; ++nt) {
                    const int o = nt * 16 + lrow;
                    #pragma unroll
                    for (int r = 0; r < 4; ++r) {
                        const int b = mbase + mt * 16 + lgrp * 4 + r;
                        tb[b * OC + o] = acc[mt][nt][r] + bb[xi][nt];
                    }
                }
        } else {
            #pragma unroll
            for (int mt = 0; mt < 2; ++mt)
                #pragma unroll
                for (int nt = 0; nt < 2; ++nt) {
                    const int o = nt * 16 + lrow;
                    #pragma unroll
                    for (int r = 0; r < 4; ++r) {
                        const int b = mbase + mt * 16 + lgrp * 4 + r;
                        outp[(size_t)(b * OC + o) * (RY * RX) + pos] = acc[mt][nt][r] + bb[xi][nt];
                    }
                }
        }
    }
}

// Phase 2: tmp[y*60+x][c] -> out[c][y*60+x], c = b*32+o in [0,4096)
__global__ __launch_bounds__(256) void lc2d_k2(
    const float* __restrict__ tmp, float* __restrict__ out)
{
    __shared__ float tile[64][61];
    const int y  = blockIdx.y;
    const int cb = blockIdx.x * 64;

    for (int i = threadIdx.x; i < RX * 16; i += 256) {
        const int xx  = i >> 4;
        const int cl4 = (i & 15) * 4;
        const float4 v = *(const float4*)(tmp + (size_t)(y * RX + xx) * (BATCH * OC) + cb + cl4);
        tile[cl4][xx]     = v.x;
        tile[cl4 + 1][xx] = v.y;
        tile[cl4 + 2][xx] = v.z;
        tile[cl4 + 3][xx] = v.w;
    }
    __syncthreads();

    for (int i = threadIdx.x; i < 64 * RX; i += 256) {
        const int cl = i / RX;
        const int xx = i % RX;
        out[(size_t)(cb + cl) * (RY * RX) + y * RX + xx] = tile[cl][xx];
    }
}

extern "C" void kernel_launch(void* const* d_in, const int* in_sizes, int n_in,
                              void* d_out, int out_size, void* d_ws, size_t ws_size,
                              hipStream_t stream) {
    const float* x    = (const float*)d_in[0];
    const float* w    = (const float*)d_in[1];
    const float* bias = (const float*)d_in[2];
    float* out        = (float*)d_out;
    float* tmp        = (float*)d_ws;

    const size_t tmp_bytes = (size_t)RY * RX * BATCH * OC * sizeof(float); // 59 MB

    if (ws_size >= tmp_bytes) {
        lc2d_k1<true><<<900, 256, 0, stream>>>(x, w, bias, out, tmp);
        lc2d_k2<<<dim3(64, RY), 256, 0, stream>>>(tmp, out);
    } else {
        lc2d_k1<false><<<900, 256, 0, stream>>>(x, w, bias, out, tmp);
    }
}

// Round 8
// 54.393 us; speedup vs baseline: 1.0275x; 1.0275x over previous
//
#include <hip/hip_runtime.h>
#include <hip/hip_bf16.h>

// Locally-connected 2D: out[b,o,y,x] = sum_{c,kh,kw} x[b,c,y+kh,x+kw] * W[y,x,o,c*25+kh*5+kw] + b[y,x,o]
// x: [128,3,64,64] f32, W: [60,60,32,75] f32, bias: [60,60,32] f32, out: [128,32,60,60] f32.
//
// k1: one block = 2 consecutive x positions (1800 blocks, XCD swizzle). k-order
// k' = (c*5+kh)*8 + w, w in [0,8) = x-window offset (slots 6,7 zero): one patch
// staging serves both positions; A-fragments hoisted to registers. W for the 2
// positions is ONE contiguous 19.2KB range -> staged into LDS as a LINEAR f32 copy
// (1200 coalesced float4 loads, no scatter/cvt on the staging path) — this kills the
// scattered-W line-visit tax that serialized rounds 2-7 (~11k lines/block -> ~1.5k).
// Lanes build B-fragments from LDS (5 x ds_read_b32 + cvt + compile-time xi shift-pack).
// ONE barrier per block; position loop is barrier-free. K'=120 pad 128 -> 4 K-steps.
// Epilogue -> tmp[pos][b*32+o] (full-line wave stores); k2 transposes tmp -> out.

#define RY 60
#define RX 60
#define OC 32
#define BATCH 128
#define CIN 3
#define HW 64
#define XT 2
#define KP 136   // pa row stride (u16); [120,136) zero pad

typedef __attribute__((ext_vector_type(8))) short short8;
typedef __attribute__((ext_vector_type(4))) float f32x4;

__device__ __forceinline__ ushort bf16u(float f) {
    __hip_bfloat16 h = __float2bfloat16(f);
    return *reinterpret_cast<ushort*>(&h);
}
__device__ __forceinline__ unsigned pk2(float a, float b) {
    return (unsigned)bf16u(a) | ((unsigned)bf16u(b) << 16);
}

template<bool COAL>
__global__ __launch_bounds__(256, 3) void lc2d_k1(
    const float* __restrict__ x, const float* __restrict__ w,
    const float* __restrict__ bias, float* __restrict__ outp,
    float* __restrict__ tmp)
{
    __shared__ ushort pa[BATCH][KP];              // 34816 B
    __shared__ __align__(16) float wtf[XT * 2400 + 8];  // 19232 B; total 54048 -> 3 blocks/CU

    const int tid = threadIdx.x;
    // XCD-chunked bijective mapping: 1800 = 8 x 225
    const int id  = blockIdx.x;
    const int lin = (id & 7) * 225 + (id >> 3);
    const int xp  = lin % 30;
    const int y   = lin / 30;
    const int x0  = xp * 2;
    const int pos0 = y * RX + x0;

    const int lane = tid & 63;
    const int lrow = lane & 15;
    const int lgrp = lane >> 4;
    const int wid  = tid >> 6;
    const int mbase = wid * 32;

    // ---- bias prefetch ----
    float bb[XT][2];
    #pragma unroll
    for (int xi = 0; xi < XT; ++xi) {
        bb[xi][0] = bias[(size_t)(pos0 + xi) * OC + lrow];
        bb[xi][1] = bias[(size_t)(pos0 + xi) * OC + 16 + lrow];
    }

    // ---- W staging: LINEAR f32 copy of the 2 positions' contiguous 19.2KB ----
    {
        const float4* w4 = (const float4*)(w + (size_t)pos0 * (OC * 75));  // 16B-aligned
        #pragma unroll
        for (int i = 0; i < 5; ++i) {
            const int idx = tid + i * 256;      // 1200 float4
            if (i < 4 || idx < 1200)
                *reinterpret_cast<float4*>(&wtf[idx * 4]) = w4[idx];
        }
    }

    // ---- patch staging: row = (b, cm=c*5+kh), 6 floats -> slots [0,6), 7,8 zero ----
    #pragma unroll
    for (int i = 0; i < 8; ++i) {
        const int r = tid + i * 256;            // 1920 rows
        if (i < 7 || r < BATCH * 15) {
            const int b  = r / 15;
            const int cm = r - b * 15;
            const int c  = cm / 5;
            const int kh = cm - c * 5;
            const float* src = x + (size_t)((b * CIN + c) * HW + (y + kh)) * HW + x0;
            const float2 v0 = *(const float2*)(src);       // x0 even -> 8B aligned
            const float2 v1 = *(const float2*)(src + 2);
            const float2 v2 = *(const float2*)(src + 4);
            *reinterpret_cast<uint4*>(&pa[b][cm * 8]) =
                make_uint4(pk2(v0.x, v0.y), pk2(v1.x, v1.y), pk2(v2.x, v2.y), 0u);
        }
    }
    if (tid < 128) {   // zero pa[b][120..136)
        *reinterpret_cast<uint4*>(&pa[tid][120]) = make_uint4(0u, 0u, 0u, 0u);
        *reinterpret_cast<uint4*>(&pa[tid][128]) = make_uint4(0u, 0u, 0u, 0u);
    }
    __syncthreads();   // the ONLY barrier

    // ---- hoist A-fragments (shared by both positions) ----
    short8 af[4][2];
    #pragma unroll
    for (int ks = 0; ks < 4; ++ks) {
        const int koff = ks * 32 + lgrp * 8;
        af[ks][0] = *(const short8*)&pa[mbase + lrow][koff];
        af[ks][1] = *(const short8*)&pa[mbase + 16 + lrow][koff];
    }

    // ---- position loop: barrier-free; B-fragments from LDS W ----
    #pragma unroll
    for (int xi = 0; xi < XT; ++xi) {
        const float* wp = &wtf[xi * 2400];

        short8 bfr[2][4];
        #pragma unroll
        for (int nt = 0; nt < 2; ++nt) {
            #pragma unroll
            for (int ks = 0; ks < 4; ++ks) {
                const int cm = ks * 4 + lgrp;                   // 0..15
                const float* s = wp + (nt * 16 + lrow) * 75 + cm * 5;  // cm==15 hits slack
                float f[5] = {s[0], s[1], s[2], s[3], s[4]};
                unsigned wd[4] = {0u, 0u, 0u, 0u};
                #pragma unroll
                for (int kw = 0; kw < 5; ++kw) {
                    const int ws = xi + kw;                     // xi compile-time
                    wd[ws >> 1] |= (unsigned)bf16u(f[kw]) << ((ws & 1) * 16);
                }
                if (cm == 15) { wd[0] = 0u; wd[1] = 0u; wd[2] = 0u; }  // k' >= 120
                union { unsigned u[4]; short8 s8; } cv;
                cv.u[0] = wd[0]; cv.u[1] = wd[1]; cv.u[2] = wd[2]; cv.u[3] = wd[3];
                bfr[nt][ks] = cv.s8;
            }
        }

        f32x4 acc[2][2];
        #pragma unroll
        for (int mt = 0; mt < 2; ++mt)
            #pragma unroll
            for (int nt = 0; nt < 2; ++nt)
                acc[mt][nt] = (f32x4){0.f, 0.f, 0.f, 0.f};

        #pragma unroll
        for (int ks = 0; ks < 4; ++ks) {
            acc[0][0] = __builtin_amdgcn_mfma_f32_16x16x32_bf16(af[ks][0], bfr[0][ks], acc[0][0], 0, 0, 0);
            acc[0][1] = __builtin_amdgcn_mfma_f32_16x16x32_bf16(af[ks][0], bfr[1][ks], acc[0][1], 0, 0, 0);
            acc[1][0] = __builtin_amdgcn_mfma_f32_16x16x32_bf16(af[ks][1], bfr[0][ks], acc[1][0], 0, 0, 0);
            acc[1][1] = __builtin_amdgcn_mfma_f32_16x16x32_bf16(af[ks][1], bfr[1][ks], acc[1][1], 0, 0, 0);
        }

        const int pos = pos0 + xi;
        if (COAL) {
            float* tb = tmp + (size_t)pos * (BATCH * OC);
            #pragma unroll
            for (int mt = 0; mt < 2; ++mt)
                #pragma unroll
                for (int nt = 0; nt < 2; ++nt) {
                    const int o = nt * 16 + lrow;
                    #pragma unroll
                    for (int r = 0; r < 4; ++r) {
                        const int b = mbase + mt * 16 + lgrp * 4 + r;
                        tb[b * OC + o] = acc[mt][nt][r] + bb[xi][nt];
                    }
                }
        } else {
            #pragma unroll
            for (int mt = 0; mt < 2; ++mt)
                #pragma unroll
                for (int nt = 0; nt < 2; ++nt) {
                    const int o = nt * 16 + lrow;
                    #pragma unroll
                    for (int r = 0; r < 4; ++r) {
                        const int b = mbase + mt * 16 + lgrp * 4 + r;
                        outp[(size_t)(b * OC + o) * (RY * RX) + pos] = acc[mt][nt][r] + bb[xi][nt];
                    }
                }
        }
    }
}

// Phase 2: tmp[y*60+x][c] -> out[c][y*60+x], c = b*32+o in [0,4096)
__global__ __launch_bounds__(256) void lc2d_k2(
    const float* __restrict__ tmp, float* __restrict__ out)
{
    __shared__ float tile[64][61];
    const int y  = blockIdx.y;
    const int cb = blockIdx.x * 64;

    for (int i = threadIdx.x; i < RX * 16; i += 256) {
        const int xx  = i >> 4;
        const int cl4 = (i & 15) * 4;
        const float4 v = *(const float4*)(tmp + (size_t)(y * RX + xx) * (BATCH * OC) + cb + cl4);
        tile[cl4][xx]     = v.x;
        tile[cl4 + 1][xx] = v.y;
        tile[cl4 + 2][xx] = v.z;
        tile[cl4 + 3][xx] = v.w;
    }
    __syncthreads();

    for (int i = threadIdx.x; i < 64 * RX; i += 256) {
        const int cl = i / RX;
        const int xx = i % RX;
        out[(size_t)(cb + cl) * (RY * RX) + y * RX + xx] = tile[cl][xx];
    }
}

extern "C" void kernel_launch(void* const* d_in, const int* in_sizes, int n_in,
                              void* d_out, int out_size, void* d_ws, size_t ws_size,
                              hipStream_t stream) {
    const float* x    = (const float*)d_in[0];
    const float* w    = (const float*)d_in[1];
    const float* bias = (const float*)d_in[2];
    float* out        = (float*)d_out;
    float* tmp        = (float*)d_ws;

    const size_t tmp_bytes = (size_t)RY * RX * BATCH * OC * sizeof(float); // 59 MB

    if (ws_size >= tmp_bytes) {
        lc2d_k1<true><<<1800, 256, 0, stream>>>(x, w, bias, out, tmp);
        lc2d_k2<<<dim3(64, RY), 256, 0, stream>>>(tmp, out);
    } else {
        lc2d_k1<false><<<1800, 256, 0, stream>>>(x, w, bias, out, tmp);
    }
}

// Round 9
// 42.195 us; speedup vs baseline: 1.3245x; 1.2891x over previous
//
#include <hip/hip_runtime.h>
#include <hip/hip_bf16.h>

// Locally-connected 2D: out[b,o,y,x] = sum_{c,kh,kw} x[b,c,y+kh,x+kw] * W[y,x,o,c*25+kh*5+kw] + b[y,x,o]
// x: [128,3,64,64] f32, W: [60,60,32,75] f32, bias: [60,60,32] f32, out: [128,32,60,60] f32.
//
// k1: one block = 4 consecutive x positions (900 blocks, bijective XCD swizzle).
// k-order k' = (c*5+kh)*8 + w, w in [0,8) = x-window offset.
// - NO patch LDS: each (b,cm) row feeds exactly one lane -> lanes load their
//   A-fragments (8 aligned floats) DIRECTLY from global (16 independent loads).
// - W (contiguous 38.4KB for 4 positions) staged f32 into LDS via async
//   __builtin_amdgcn_global_load_lds width-16 (38 wave-instrs, no VGPR round trip).
// - ONE barrier; position loop barrier-free; B-frags = 5 ds_read_b32 + cvt +
//   compile-time xi shift-pack (W slots outside [xi,xi+5) are zero).
// - tmp in BF16 (final-value rounding ~0.011 abs, threshold 0.118): halves writes.
// k2 transposes bf16 tmp -> f32 out. Fallback: direct f32 scatter if ws too small.

#define RY 60
#define RX 60
#define OC 32
#define BATCH 128
#define CIN 3
#define HW 64
#define XT 4

typedef __attribute__((ext_vector_type(8))) short short8;
typedef __attribute__((ext_vector_type(4))) float f32x4;

__device__ __forceinline__ ushort bf16u(float f) {
    __hip_bfloat16 h = __float2bfloat16(f);
    return *reinterpret_cast<ushort*>(&h);
}
__device__ __forceinline__ unsigned pk2(float a, float b) {
    return (unsigned)bf16u(a) | ((unsigned)bf16u(b) << 16);
}

template<bool COAL>
__global__ __launch_bounds__(256, 4) void lc2d_k1(
    const float* __restrict__ x, const float* __restrict__ w,
    const float* __restrict__ bias, float* __restrict__ outp,
    ushort* __restrict__ tmp)
{
    __shared__ __align__(16) float wlds[XT * 2400 + 128];  // 38912 B -> 4 blocks/CU

    const int tid = threadIdx.x;
    // bijective XCD swizzle for 900 blocks: chunks 113x4 + 112x4
    const int id  = blockIdx.x;
    const int xcd = id & 7, ii = id >> 3;
    const int lin = (xcd < 4 ? xcd * 113 : 452 + (xcd - 4) * 112) + ii;
    const int y   = lin / 15;
    const int xg  = lin - y * 15;
    const int x0  = xg * 4;                 // multiple of 4 -> 16B-aligned x loads
    const int pos0 = y * RX + x0;

    const int lane = tid & 63;
    const int lrow = lane & 15;
    const int lgrp = lane >> 4;
    const int wid  = tid >> 6;
    const int mbase = wid * 32;

    // ---- A-fragments, first half (ks 0,1): direct global loads ----
    float4 av[2][2][2];                     // [ks][mt][half]
    #pragma unroll
    for (int ks = 0; ks < 2; ++ks) {
        const int cm = ks * 4 + lgrp;       // < 15 always for ks<2? max 1*4+3=7 yes
        const int c  = cm / 5;
        const int kh = cm - c * 5;
        #pragma unroll
        for (int mt = 0; mt < 2; ++mt) {
            const int b = mbase + mt * 16 + lrow;
            const float* src = x + (size_t)((b * CIN + c) * HW + (y + kh)) * HW + x0;
            av[ks][mt][0] = *(const float4*)(src);
            av[ks][mt][1] = *(const float4*)(src + 4);
        }
    }

    // ---- async W DMA: 38.4KB contiguous f32, 16B/lane, 38 wave-calls ----
    {
        const float* gW = w + (size_t)pos0 * 2400;
        for (int j = wid; j < 38; j += 4) {
            const int chunk0 = j * 64;              // wave-uniform
            int ci = chunk0 + lane;
            if (ci > 2399) ci = 2399;               // clamp overshoot (lands in pad)
            __builtin_amdgcn_global_load_lds(
                (const __attribute__((address_space(1))) unsigned*)(gW + ci * 4),
                (__attribute__((address_space(3))) unsigned*)&wlds[chunk0 * 4],
                16, 0, 0);
        }
    }

    // ---- bias prefetch ----
    float bb[XT][2];
    #pragma unroll
    for (int xi = 0; xi < XT; ++xi) {
        bb[xi][0] = bias[(size_t)(pos0 + xi) * OC + lrow];
        bb[xi][1] = bias[(size_t)(pos0 + xi) * OC + 16 + lrow];
    }

    // ---- pack first half, load+pack second half ----
    short8 af[4][2];
    #pragma unroll
    for (int ks = 0; ks < 2; ++ks)
        #pragma unroll
        for (int mt = 0; mt < 2; ++mt) {
            union { unsigned u[4]; short8 s8; } cv;
            cv.u[0] = pk2(av[ks][mt][0].x, av[ks][mt][0].y);
            cv.u[1] = pk2(av[ks][mt][0].z, av[ks][mt][0].w);
            cv.u[2] = pk2(av[ks][mt][1].x, av[ks][mt][1].y);
            cv.u[3] = pk2(av[ks][mt][1].z, av[ks][mt][1].w);
            af[ks][mt] = cv.s8;
        }
    #pragma unroll
    for (int ks = 2; ks < 4; ++ks) {
        const int cm = ks * 4 + lgrp;
        if (cm < 15) {
            const int c  = cm / 5;
            const int kh = cm - c * 5;
            #pragma unroll
            for (int mt = 0; mt < 2; ++mt) {
                const int b = mbase + mt * 16 + lrow;
                const float* src = x + (size_t)((b * CIN + c) * HW + (y + kh)) * HW + x0;
                const float4 v0 = *(const float4*)(src);
                const float4 v1 = *(const float4*)(src + 4);
                union { unsigned u[4]; short8 s8; } cv;
                cv.u[0] = pk2(v0.x, v0.y);
                cv.u[1] = pk2(v0.z, v0.w);
                cv.u[2] = pk2(v1.x, v1.y);
                cv.u[3] = pk2(v1.z, v1.w);
                af[ks][mt] = cv.s8;
            }
        } else {
            #pragma unroll
            for (int mt = 0; mt < 2; ++mt)
                af[ks][mt] = (short8){0,0,0,0,0,0,0,0};
        }
    }

    __syncthreads();   // the ONLY barrier (drains W DMA for all waves)

    // ---- position loop: barrier-free ----
    #pragma unroll
    for (int xi = 0; xi < XT; ++xi) {
        const float* wp = &wlds[xi * 2400];

        short8 bfr[2][4];
        #pragma unroll
        for (int nt = 0; nt < 2; ++nt) {
            #pragma unroll
            for (int ks = 0; ks < 4; ++ks) {
                const int cm = ks * 4 + lgrp;
                unsigned wd[4] = {0u, 0u, 0u, 0u};
                if (cm < 15) {
                    const float* s = wp + (nt * 16 + lrow) * 75 + cm * 5;
                    const float f[5] = {s[0], s[1], s[2], s[3], s[4]};
                    #pragma unroll
                    for (int kw = 0; kw < 5; ++kw) {
                        const int ws = xi + kw;             // xi compile-time
                        wd[ws >> 1] |= (unsigned)bf16u(f[kw]) << ((ws & 1) * 16);
                    }
                }
                union { unsigned u[4]; short8 s8; } cv;
                cv.u[0] = wd[0]; cv.u[1] = wd[1]; cv.u[2] = wd[2]; cv.u[3] = wd[3];
                bfr[nt][ks] = cv.s8;
            }
        }

        f32x4 acc[2][2];
        #pragma unroll
        for (int mt = 0; mt < 2; ++mt)
            #pragma unroll
            for (int nt = 0; nt < 2; ++nt)
                acc[mt][nt] = (f32x4){0.f, 0.f, 0.f, 0.f};

        #pragma unroll
        for (int ks = 0; ks < 4; ++ks) {
            acc[0][0] = __builtin_amdgcn_mfma_f32_16x16x32_bf16(af[ks][0], bfr[0][ks], acc[0][0], 0, 0, 0);
            acc[0][1] = __builtin_amdgcn_mfma_f32_16x16x32_bf16(af[ks][0], bfr[1][ks], acc[0][1], 0, 0, 0);
            acc[1][0] = __builtin_amdgcn_mfma_f32_16x16x32_bf16(af[ks][1], bfr[0][ks], acc[1][0], 0, 0, 0);
            acc[1][1] = __builtin_amdgcn_mfma_f32_16x16x32_bf16(af[ks][1], bfr[1][ks], acc[1][1], 0, 0, 0);
        }

        const int pos = pos0 + xi;
        if (COAL) {
            ushort* tb = tmp + (size_t)pos * (BATCH * OC);
            #pragma unroll
            for (int mt = 0; mt < 2; ++mt)
                #pragma unroll
                for (int nt = 0; nt < 2; ++nt) {
                    const int o = nt * 16 + lrow;
                    #pragma unroll
                    for (int r = 0; r < 4; ++r) {
                        const int b = mbase + mt * 16 + lgrp * 4 + r;
                        tb[b * OC + o] = bf16u(acc[mt][nt][r] + bb[xi][nt]);
                    }
                }
        } else {
            #pragma unroll
            for (int mt = 0; mt < 2; ++mt)
                #pragma unroll
                for (int nt = 0; nt < 2; ++nt) {
                    const int o = nt * 16 + lrow;
                    #pragma unroll
                    for (int r = 0; r < 4; ++r) {
                        const int b = mbase + mt * 16 + lgrp * 4 + r;
                        outp[(size_t)(b * OC + o) * (RY * RX) + pos] = acc[mt][nt][r] + bb[xi][nt];
                    }
                }
        }
    }
}

// Phase 2: tmp bf16 [y*60+x][c] -> out f32 [c][y*60+x], c = b*32+o in [0,4096)
__global__ __launch_bounds__(256) void lc2d_k2(
    const ushort* __restrict__ tmp, float* __restrict__ out)
{
    __shared__ float tile[64][61];
    const int y  = blockIdx.y;
    const int cb = blockIdx.x * 64;

    for (int i = threadIdx.x; i < RX * 32; i += 256) {
        const int xx = i >> 5;
        const int cp = i & 31;
        const unsigned u = *(const unsigned*)(tmp + (size_t)(y * RX + xx) * (BATCH * OC) + cb + cp * 2);
        tile[cp * 2][xx]     = __uint_as_float(u << 16);
        tile[cp * 2 + 1][xx] = __uint_as_float(u & 0xffff0000u);
    }
    __syncthreads();

    for (int i = threadIdx.x; i < 64 * RX; i += 256) {
        const int cl = i / RX;
        const int xx = i % RX;
        out[(size_t)(cb + cl) * (RY * RX) + y * RX + xx] = tile[cl][xx];
    }
}

extern "C" void kernel_launch(void* const* d_in, const int* in_sizes, int n_in,
                              void* d_out, int out_size, void* d_ws, size_t ws_size,
                              hipStream_t stream) {
    const float* x    = (const float*)d_in[0];
    const float* w    = (const float*)d_in[1];
    const float* bias = (const float*)d_in[2];
    float* out        = (float*)d_out;
    ushort* tmp       = (ushort*)d_ws;

    const size_t tmp_bytes = (size_t)RY * RX * BATCH * OC * sizeof(ushort); // 29.5 MB

    if (ws_size >= tmp_bytes) {
        lc2d_k1<true><<<900, 256, 0, stream>>>(x, w, bias, out, tmp);
        lc2d_k2<<<dim3(64, RY), 256, 0, stream>>>(tmp, out);
    } else {
        lc2d_k1<false><<<900, 256, 0, stream>>>(x, w, bias, out, tmp);
    }
}